// Round 10
// baseline (314.208 us; speedup 1.0000x reference)
//
#include <hip/hip_runtime.h>
#include <hip/hip_bf16.h>

// Problem constants (fixed by the reference).
#define NNODES 10000
#define NEDGES 160000
#define FIN    2208
#define HDIM   512
#define NCLS   2

#define MPAD   10240     // 80 * 128
#define K1PAD  2240      // 2208 padded to multiple of 64
#define BCAP   128       // per-node edge bucket capacity (max degree ~35 here)

typedef __bf16 bf16x8 __attribute__((ext_vector_type(8)));
typedef float  f32x4  __attribute__((ext_vector_type(4)));
typedef unsigned short u16x8 __attribute__((ext_vector_type(8)));

__device__ inline unsigned short f2bf(float f) {
    union { float f; unsigned int u; } v; v.f = f;
    return (unsigned short)((v.u + 0x7FFFu + ((v.u >> 16) & 1u)) >> 16);
}
__device__ inline float bf2f(unsigned short u) {
    union { unsigned int i; float f; } v; v.i = ((unsigned int)u) << 16; return v.f;
}

// ---------------- dispatch 1: LDS-tiled weight transposes + cnt zero ----------
// 64x64 fp32 tiles: coalesced global reads (consecutive n) AND coalesced
// transposed writes (consecutive k). 65-float pitch -> <=2-way LDS conflicts
// (free). Blocks: W1 280 (35x8), W2 64, W3 64, cnt-zero 40 => 448.
__global__ __launch_bounds__(256) void k_prep(
    const float* __restrict__ W1, const float* __restrict__ W2,
    const float* __restrict__ W3, unsigned short* __restrict__ W1t,
    unsigned short* __restrict__ W2t, unsigned short* __restrict__ W3t,
    int* __restrict__ cnt) {
    int bx = blockIdx.x;
    if (bx >= 408) {                       // cnt zero
        int i = (bx - 408) * 256 + threadIdx.x;
        if (i < NNODES) cnt[i] = 0;
        return;
    }
    __shared__ float tile[64][65];
    const float* W; unsigned short* Wt; int kt, nt, Kreal, Kp;
    if (bx < 280)      { W = W1; Wt = W1t; kt = bx % 35; nt = bx / 35; Kreal = FIN;  Kp = K1PAD; }
    else if (bx < 344) { int b = bx - 280; W = W2; Wt = W2t; kt = b % 8; nt = b / 8; Kreal = HDIM; Kp = HDIM; }
    else               { int b = bx - 344; W = W3; Wt = W3t; kt = b % 8; nt = b / 8; Kreal = HDIM; Kp = HDIM; }
    int t  = threadIdx.x;
    int ln = t & 63;
    int lr = t >> 6;
    int k0 = kt * 64, n0 = nt * 64;
    #pragma unroll
    for (int i = 0; i < 16; ++i) {
        int lk = i * 4 + lr;
        int k = k0 + lk;
        tile[lk][ln] = (k < Kreal) ? W[(size_t)k * HDIM + n0 + ln] : 0.0f;
    }
    __syncthreads();
    #pragma unroll
    for (int i = 0; i < 16; ++i) {
        int lnn = i * 4 + lr;
        Wt[(size_t)(n0 + lnn) * Kp + k0 + ln] = f2bf(tile[ln][lnn]);
    }
}

// ---------------- dispatch 2: x->bf16 convert + bucketed hist/fill -----------
// (R5 lesson: convert must NOT fuse into GEMM1's LDS staging.)
__global__ void k_cvt_fill(const float* __restrict__ x, unsigned short* __restrict__ xb,
                           const int* __restrict__ ei, int* __restrict__ cnt,
                           int* __restrict__ bucket) {
    int bx = blockIdx.x;
    int t = threadIdx.x;
    if (bx >= MPAD) {                      // hist+fill part
        int i = (bx - MPAD) * 256 + t;
        if (i < NEDGES) {
            int src = ei[i];
            int dst = ei[NEDGES + i];
            int pos = atomicAdd(&cnt[dst], 1);
            bucket[dst * BCAP + pos] = src;
        }
        return;
    }
    int row = bx;                          // convert part
    unsigned short* orow = xb + (size_t)row * K1PAD;
    u16x8 z = {0, 0, 0, 0, 0, 0, 0, 0};
    if (row >= NNODES) {
        for (int c = t; c < K1PAD / 8; c += 256) *(u16x8*)(orow + c * 8) = z;
        return;
    }
    const float* irow = x + (size_t)row * FIN;
    for (int c = t; c < K1PAD / 8; c += 256) {
        int col = c * 8;
        u16x8 o = z;
        if (col + 8 <= FIN) {
            float4 f0 = *(const float4*)(irow + col);
            float4 f1 = *(const float4*)(irow + col + 4);
            o[0] = f2bf(f0.x); o[1] = f2bf(f0.y); o[2] = f2bf(f0.z); o[3] = f2bf(f0.w);
            o[4] = f2bf(f1.x); o[5] = f2bf(f1.y); o[6] = f2bf(f1.z); o[7] = f2bf(f1.w);
        }
        *(u16x8*)(orow + col) = o;
    }
}

// ---------------- bf16 MFMA GEMM body (shared by layers 1-3) ----------------
#define BKK 64
#define GG1 640

__device__ __forceinline__ void gemm_body(
    const unsigned short* __restrict__ A, const unsigned short* __restrict__ Bt,
    unsigned short* __restrict__ C, int M, int K, int l) {
    __shared__ char As[128 * BKK * 2] __attribute__((aligned(16)));
    __shared__ char Bs[64 * BKK * 2]  __attribute__((aligned(16)));
    const int tid  = threadIdx.x;
    const int lane = tid & 63;
    const int w    = tid >> 6;
    const int wm   = w & 1, wn = w >> 1;
    const int quad = lane >> 4, lq = lane & 15;

    const int xcd   = l & 7;
    const int q     = l >> 3;
    const int strip = (q >> 3) * 8 + xcd;
    const int bm    = strip * 128;
    const int bn    = (q & 7) * 64;

    f32x4 acc[4][2] = {};

    for (int k0 = 0; k0 < K; k0 += BKK) {
        #pragma unroll
        for (int i = 0; i < 4; ++i) {
            int c = i * 256 + tid;
            int r = c >> 3;
            int g = (c & 7) ^ (r & 7);
            const char* gpA = (const char*)A + ((size_t)(bm + r) * K + k0) * 2 + (g << 4);
            __builtin_amdgcn_global_load_lds(
                (const __attribute__((address_space(1))) void*)gpA,
                (__attribute__((address_space(3))) void*)(As + c * 16), 16, 0, 0);
        }
        #pragma unroll
        for (int i = 0; i < 2; ++i) {
            int c = i * 256 + tid;
            int r = c >> 3;
            int g = (c & 7) ^ (r & 7);
            const char* gpB = (const char*)Bt + ((size_t)(bn + r) * K + k0) * 2 + (g << 4);
            __builtin_amdgcn_global_load_lds(
                (const __attribute__((address_space(1))) void*)gpB,
                (__attribute__((address_space(3))) void*)(Bs + c * 16), 16, 0, 0);
        }
        __syncthreads();

        #pragma unroll
        for (int s = 0; s < 2; ++s) {
            bf16x8 af[4], bfr[2];
            int g = s * 4 + quad;
            #pragma unroll
            for (int i = 0; i < 4; ++i) {
                int r = wm * 64 + i * 16 + lq;
                af[i] = *(const bf16x8*)(As + r * 128 + ((g ^ (r & 7)) << 4));
            }
            #pragma unroll
            for (int j = 0; j < 2; ++j) {
                int n = wn * 32 + j * 16 + lq;
                bfr[j] = *(const bf16x8*)(Bs + n * 128 + ((g ^ (n & 7)) << 4));
            }
            #pragma unroll
            for (int i = 0; i < 4; ++i)
                #pragma unroll
                for (int j = 0; j < 2; ++j)
                    acc[i][j] = __builtin_amdgcn_mfma_f32_16x16x32_bf16(
                        af[i], bfr[j], acc[i][j], 0, 0, 0);
        }
        __syncthreads();
    }

    #pragma unroll
    for (int i = 0; i < 4; ++i) {
        #pragma unroll
        for (int p = 0; p < 4; ++p) {
            int r = bm + wm * 64 + i * 16 + quad * 4 + p;
            if (r < M) {
                #pragma unroll
                for (int j = 0; j < 2; ++j) {
                    int col = bn + wn * 32 + j * 16 + lq;
                    C[(size_t)r * HDIM + col] = f2bf(acc[i][j][p]);
                }
            }
        }
    }
}

// ---------------- dispatch 3: GEMM1 (640 blocks) + dinv compute (40) ----------
__global__ __launch_bounds__(256) void k_gemm1_dinv(
    const unsigned short* __restrict__ A, const unsigned short* __restrict__ Bt,
    unsigned short* __restrict__ C, int M, int K,
    const int* __restrict__ cnt, float* __restrict__ dinv) {
    int bx = blockIdx.x;
    if (bx < GG1) { gemm_body(A, Bt, C, M, K, bx); return; }
    int i = (bx - GG1) * 256 + threadIdx.x;
    if (i < NNODES) dinv[i] = rsqrtf((float)cnt[i] + 1.0f);
}

// ---------------- GEMM (layers 2/3) ----------------
__global__ __launch_bounds__(256) void k_gemm_bf16(
    const unsigned short* __restrict__ A, const unsigned short* __restrict__ Bt,
    unsigned short* __restrict__ C, int M, int K) {
    gemm_body(A, Bt, C, M, K, blockIdx.x);
}

// ---------------- 8-row gather batch: edge partial accumulate ----------------
// Issues all 8 row-gathers before any FMA -> ~8 loads in flight per wave
// (vs ~4 with the old unroll). Edge order preserved -> bit-identical sums.
__device__ __forceinline__ void agg_edges(const unsigned short* __restrict__ Y,
                                          const float* __restrict__ dinv, float di,
                                          const int* __restrict__ col, int deg,
                                          int lane, float acc[8]) {
    int e = 0;
    for (; e + 8 <= deg; e += 8) {
        int s0 = col[e + 0], s1 = col[e + 1], s2 = col[e + 2], s3 = col[e + 3];
        int s4 = col[e + 4], s5 = col[e + 5], s6 = col[e + 6], s7 = col[e + 7];
        u16x8 v0 = *(const u16x8*)(Y + (size_t)s0 * HDIM + lane * 8);
        u16x8 v1 = *(const u16x8*)(Y + (size_t)s1 * HDIM + lane * 8);
        u16x8 v2 = *(const u16x8*)(Y + (size_t)s2 * HDIM + lane * 8);
        u16x8 v3 = *(const u16x8*)(Y + (size_t)s3 * HDIM + lane * 8);
        u16x8 v4 = *(const u16x8*)(Y + (size_t)s4 * HDIM + lane * 8);
        u16x8 v5 = *(const u16x8*)(Y + (size_t)s5 * HDIM + lane * 8);
        u16x8 v6 = *(const u16x8*)(Y + (size_t)s6 * HDIM + lane * 8);
        u16x8 v7 = *(const u16x8*)(Y + (size_t)s7 * HDIM + lane * 8);
        float w0 = di * dinv[s0], w1 = di * dinv[s1];
        float w2 = di * dinv[s2], w3 = di * dinv[s3];
        float w4 = di * dinv[s4], w5 = di * dinv[s5];
        float w6 = di * dinv[s6], w7 = di * dinv[s7];
        #pragma unroll
        for (int t = 0; t < 8; ++t) {
            acc[t] += w0 * bf2f(v0[t]);
            acc[t] += w1 * bf2f(v1[t]);
            acc[t] += w2 * bf2f(v2[t]);
            acc[t] += w3 * bf2f(v3[t]);
            acc[t] += w4 * bf2f(v4[t]);
            acc[t] += w5 * bf2f(v5[t]);
            acc[t] += w6 * bf2f(v6[t]);
            acc[t] += w7 * bf2f(v7[t]);
        }
    }
    for (; e + 4 <= deg; e += 4) {
        int s0 = col[e + 0], s1 = col[e + 1], s2 = col[e + 2], s3 = col[e + 3];
        u16x8 v0 = *(const u16x8*)(Y + (size_t)s0 * HDIM + lane * 8);
        u16x8 v1 = *(const u16x8*)(Y + (size_t)s1 * HDIM + lane * 8);
        u16x8 v2 = *(const u16x8*)(Y + (size_t)s2 * HDIM + lane * 8);
        u16x8 v3 = *(const u16x8*)(Y + (size_t)s3 * HDIM + lane * 8);
        float w0 = di * dinv[s0], w1 = di * dinv[s1];
        float w2 = di * dinv[s2], w3 = di * dinv[s3];
        #pragma unroll
        for (int t = 0; t < 8; ++t) {
            acc[t] += w0 * bf2f(v0[t]);
            acc[t] += w1 * bf2f(v1[t]);
            acc[t] += w2 * bf2f(v2[t]);
            acc[t] += w3 * bf2f(v3[t]);
        }
    }
    for (; e < deg; ++e) {
        int s = col[e];
        float wg = di * dinv[s];
        u16x8 v = *(const u16x8*)(Y + (size_t)s * HDIM + lane * 8);
        #pragma unroll
        for (int t = 0; t < 8; ++t) acc[t] += wg * bf2f(v[t]);
    }
}

// ---------------- aggregation (layers 1/2): 1 wave per node ----------------

__global__ __launch_bounds__(256) void k_agg(
    const unsigned short* __restrict__ Y, const float* __restrict__ dinv,
    const int* __restrict__ cnt, const int* __restrict__ bucket,
    const float* __restrict__ bias, unsigned short* __restrict__ Hb) {
    int w = (blockIdx.x * blockDim.x + threadIdx.x) >> 6;
    int lane = threadIdx.x & 63;
    if (w >= MPAD) return;
    unsigned short* hr = Hb + (size_t)w * HDIM + lane * 8;
    if (w >= NNODES) {
        u16x8 z = {0, 0, 0, 0, 0, 0, 0, 0};
        *(u16x8*)hr = z;
        return;
    }
    float di = dinv[w];
    float sw = di * di;
    u16x8 own = *(const u16x8*)(Y + (size_t)w * HDIM + lane * 8);
    float acc[8];
    #pragma unroll
    for (int t = 0; t < 8; ++t) acc[t] = sw * bf2f(own[t]);

    agg_edges(Y, dinv, di, bucket + w * BCAP, cnt[w], lane, acc);

    float4 b0 = ((const float4*)bias)[lane * 2];
    float4 b1 = ((const float4*)bias)[lane * 2 + 1];
    acc[0] += b0.x; acc[1] += b0.y; acc[2] += b0.z; acc[3] += b0.w;
    acc[4] += b1.x; acc[5] += b1.y; acc[6] += b1.z; acc[7] += b1.w;
    u16x8 o;
    #pragma unroll
    for (int t = 0; t < 8; ++t) o[t] = f2bf(fmaxf(acc[t], 0.0f));
    *(u16x8*)hr = o;
}

// ---------------- agg3 + relu + layer-4 GEMM fused ----------------

__global__ __launch_bounds__(256) void k_agg_g4(
    const unsigned short* __restrict__ Y, const float* __restrict__ dinv,
    const int* __restrict__ cnt, const int* __restrict__ bucket,
    const float* __restrict__ b3, const float* __restrict__ W4,
    float* __restrict__ Y4) {
    int w = (blockIdx.x * blockDim.x + threadIdx.x) >> 6;
    int lane = threadIdx.x & 63;
    if (w >= NNODES) return;
    float di = dinv[w];
    float sw = di * di;
    u16x8 own = *(const u16x8*)(Y + (size_t)w * HDIM + lane * 8);
    float acc[8];
    #pragma unroll
    for (int t = 0; t < 8; ++t) acc[t] = sw * bf2f(own[t]);

    agg_edges(Y, dinv, di, bucket + w * BCAP, cnt[w], lane, acc);

    float4 b0 = ((const float4*)b3)[lane * 2];
    float4 b1 = ((const float4*)b3)[lane * 2 + 1];
    acc[0] += b0.x; acc[1] += b0.y; acc[2] += b0.z; acc[3] += b0.w;
    acc[4] += b1.x; acc[5] += b1.y; acc[6] += b1.z; acc[7] += b1.w;
    #pragma unroll
    for (int t = 0; t < 8; ++t) acc[t] = fmaxf(acc[t], 0.0f);

    const float4* wf = (const float4*)W4;
    float4 w0 = wf[lane * 4 + 0];
    float4 w1 = wf[lane * 4 + 1];
    float4 w2 = wf[lane * 4 + 2];
    float4 w3 = wf[lane * 4 + 3];
    float z0 = acc[0]*w0.x + acc[1]*w0.z + acc[2]*w1.x + acc[3]*w1.z
             + acc[4]*w2.x + acc[5]*w2.z + acc[6]*w3.x + acc[7]*w3.z;
    float z1 = acc[0]*w0.y + acc[1]*w0.w + acc[2]*w1.y + acc[3]*w1.w
             + acc[4]*w2.y + acc[5]*w2.w + acc[6]*w3.y + acc[7]*w3.w;
    #pragma unroll
    for (int off = 32; off > 0; off >>= 1) {
        z0 += __shfl_down(z0, off);
        z1 += __shfl_down(z1, off);
    }
    if (lane == 0) {
        Y4[2 * w] = z0;
        Y4[2 * w + 1] = z1;
    }
}

// ---------------- layer-4 aggregation + bias + log_softmax ----------------

__global__ void k_final(const float* __restrict__ Y4, const float* __restrict__ dinv,
                        const int* __restrict__ cnt, const int* __restrict__ bucket,
                        const float* __restrict__ b4, float* __restrict__ out, int n) {
    int i = blockIdx.x * blockDim.x + threadIdx.x;
    if (i >= n) return;
    float di = dinv[i];
    float sw = di * di;
    float z0 = sw * Y4[2 * i];
    float z1 = sw * Y4[2 * i + 1];
    const int* col = bucket + i * BCAP;
    int deg = cnt[i];
    for (int e = 0; e < deg; ++e) {
        int s = col[e];
        float wgt = di * dinv[s];
        z0 += wgt * Y4[2 * s];
        z1 += wgt * Y4[2 * s + 1];
    }
    z0 += b4[0];
    z1 += b4[1];
    float m = fmaxf(z0, z1);
    float l = m + logf(expf(z0 - m) + expf(z1 - m));
    out[2 * i] = z0 - l;
    out[2 * i + 1] = z1 - l;
}

// ---------------- launch ----------------

extern "C" void kernel_launch(void* const* d_in, const int* in_sizes, int n_in,
                              void* d_out, int out_size, void* d_ws, size_t ws_size,
                              hipStream_t stream) {
    const float* x  = (const float*)d_in[0];
    const int*   ei = (const int*)d_in[1];
    const float* W1 = (const float*)d_in[3];
    const float* b1 = (const float*)d_in[4];
    const float* W2 = (const float*)d_in[5];
    const float* b2 = (const float*)d_in[6];
    const float* W3 = (const float*)d_in[7];
    const float* b3 = (const float*)d_in[8];
    const float* W4 = (const float*)d_in[9];
    const float* b4 = (const float*)d_in[10];
    float* out = (float*)d_out;

    char* ws = (char*)d_ws;
    // workspace layout (bytes, 256-aligned)
    float*          dinv    = (float*)(ws + 0);                  // 40,960
    int*            cnt     = (int*)  (ws + 40960);              // 40,960
    int*            bucket  = (int*)  (ws + 81920);              // 5,120,000
    float*          Y4      = (float*)(ws + 5201920);            // 81,920
    unsigned short* xb      = (unsigned short*)(ws + 5283840);   // 45,875,200
    unsigned short* W1t     = (unsigned short*)(ws + 51159040);  // 2,293,760
    unsigned short* W2t     = (unsigned short*)(ws + 53452800);  // 524,288
    unsigned short* W3t     = (unsigned short*)(ws + 53977088);  // 524,288
    unsigned short* Yb      = (unsigned short*)(ws + 54501376);  // 10,485,760
    unsigned short* Hb      = (unsigned short*)(ws + 64987136);  // 10,485,760
    // total: 75,472,896
    if (ws_size < 75472896) return;

    const int agrid = (MPAD * 64) / 256;  // one wave per (padded) node

    // d1: tiled weight transposes + cnt zero
    k_prep<<<448, 256, 0, stream>>>(W1, W2, W3, W1t, W2t, W3t, cnt);
    // d2: x->bf16 convert + bucketed hist/fill
    k_cvt_fill<<<MPAD + 625, 256, 0, stream>>>(x, xb, ei, cnt, bucket);
    // d3: layer-1 GEMM + dinv compute
    k_gemm1_dinv<<<GG1 + 40, 256, 0, stream>>>(xb, W1t, Yb, NNODES, K1PAD, cnt, dinv);
    // d4: layer-1 aggregation
    k_agg<<<agrid, 256, 0, stream>>>(Yb, dinv, cnt, bucket, b1, Hb);
    // d5/d6: layer 2
    k_gemm_bf16<<<GG1, 256, 0, stream>>>(Hb, W2t, Yb, NNODES, HDIM);
    k_agg<<<agrid, 256, 0, stream>>>(Yb, dinv, cnt, bucket, b2, Hb);
    // d7/d8: layer 3 + fused layer-4 GEMM
    k_gemm_bf16<<<GG1, 256, 0, stream>>>(Hb, W3t, Yb, NNODES, HDIM);
    k_agg_g4<<<(NNODES * 64) / 256, 256, 0, stream>>>(Yb, dinv, cnt, bucket, b3, W4, Y4);
    // d9: layer-4 aggregation + log_softmax
    k_final<<<40, 256, 0, stream>>>(Y4, dinv, cnt, bucket, b4, out, NNODES);
}

// Round 11
// 307.949 us; speedup vs baseline: 1.0203x; 1.0203x over previous
//
#include <hip/hip_runtime.h>
#include <hip/hip_bf16.h>

// Problem constants (fixed by the reference).
#define NNODES 10000
#define NEDGES 160000
#define FIN    2208
#define HDIM   512
#define NCLS   2

#define MPAD   10240     // 80 * 128
#define K1PAD  2240      // 2208 padded to multiple of 64
#define BCAP   128       // per-node edge bucket capacity (max degree ~35 here)

typedef __bf16 bf16x8 __attribute__((ext_vector_type(8)));
typedef float  f32x4  __attribute__((ext_vector_type(4)));
typedef unsigned short u16x8 __attribute__((ext_vector_type(8)));

__device__ inline unsigned short f2bf(float f) {
    union { float f; unsigned int u; } v; v.f = f;
    return (unsigned short)((v.u + 0x7FFFu + ((v.u >> 16) & 1u)) >> 16);
}
__device__ inline float bf2f(unsigned short u) {
    union { unsigned int i; float f; } v; v.i = ((unsigned int)u) << 16; return v.f;
}

// ---------------- dispatch 1: weight transposes + cnt zero ----------------
// grid (14, 512): bx 0-8 -> W1t, 9-10 -> W2t, 11-12 -> W3t, 13 -> cnt zero
__global__ void k_prep(const float* __restrict__ W1, const float* __restrict__ W2,
                       const float* __restrict__ W3, unsigned short* __restrict__ W1t,
                       unsigned short* __restrict__ W2t, unsigned short* __restrict__ W3t,
                       int* __restrict__ cnt) {
    int n = blockIdx.y;
    int bx = blockIdx.x;
    int t = threadIdx.x;
    if (bx < 9) {
        int k = bx * 256 + t;
        if (k < K1PAD) {
            float v = (k < FIN) ? W1[(size_t)k * HDIM + n] : 0.0f;
            W1t[(size_t)n * K1PAD + k] = f2bf(v);
        }
    } else if (bx < 11) {
        int k = (bx - 9) * 256 + t;
        W2t[(size_t)n * HDIM + k] = f2bf(W2[(size_t)k * HDIM + n]);
    } else if (bx < 13) {
        int k = (bx - 11) * 256 + t;
        W3t[(size_t)n * HDIM + k] = f2bf(W3[(size_t)k * HDIM + n]);
    } else {
        int i = n * 256 + t;
        if (i < NNODES) cnt[i] = 0;
    }
}

// ---------------- dispatch 2: x->bf16 convert + bucketed hist/fill -----------
// No prefix scan needed: edges go to fixed-stride buckets bucket[dst*BCAP+pos].
// (R5 lesson: convert must NOT fuse into GEMM1's LDS staging.)
__global__ void k_cvt_fill(const float* __restrict__ x, unsigned short* __restrict__ xb,
                           const int* __restrict__ ei, int* __restrict__ cnt,
                           int* __restrict__ bucket) {
    int bx = blockIdx.x;
    int t = threadIdx.x;
    if (bx >= MPAD) {                      // hist+fill part
        int i = (bx - MPAD) * 256 + t;
        if (i < NEDGES) {
            int src = ei[i];
            int dst = ei[NEDGES + i];
            int pos = atomicAdd(&cnt[dst], 1);
            bucket[dst * BCAP + pos] = src;
        }
        return;
    }
    int row = bx;                          // convert part
    unsigned short* orow = xb + (size_t)row * K1PAD;
    u16x8 z = {0, 0, 0, 0, 0, 0, 0, 0};
    if (row >= NNODES) {
        for (int c = t; c < K1PAD / 8; c += 256) *(u16x8*)(orow + c * 8) = z;
        return;
    }
    const float* irow = x + (size_t)row * FIN;
    for (int c = t; c < K1PAD / 8; c += 256) {
        int col = c * 8;
        u16x8 o = z;
        if (col + 8 <= FIN) {
            float4 f0 = *(const float4*)(irow + col);
            float4 f1 = *(const float4*)(irow + col + 4);
            o[0] = f2bf(f0.x); o[1] = f2bf(f0.y); o[2] = f2bf(f0.z); o[3] = f2bf(f0.w);
            o[4] = f2bf(f1.x); o[5] = f2bf(f1.y); o[6] = f2bf(f1.z); o[7] = f2bf(f1.w);
        }
        *(u16x8*)(orow + col) = o;
    }
}

// ---------------- bf16 MFMA GEMM body (shared by layers 1-3) ----------------
#define BKK 64
#define GG1 640

__device__ __forceinline__ void gemm_body(
    const unsigned short* __restrict__ A, const unsigned short* __restrict__ Bt,
    unsigned short* __restrict__ C, int M, int K, int l) {
    __shared__ char As[128 * BKK * 2] __attribute__((aligned(16)));
    __shared__ char Bs[64 * BKK * 2]  __attribute__((aligned(16)));
    const int tid  = threadIdx.x;
    const int lane = tid & 63;
    const int w    = tid >> 6;
    const int wm   = w & 1, wn = w >> 1;
    const int quad = lane >> 4, lq = lane & 15;

    const int xcd   = l & 7;
    const int q     = l >> 3;
    const int strip = (q >> 3) * 8 + xcd;
    const int bm    = strip * 128;
    const int bn    = (q & 7) * 64;

    f32x4 acc[4][2] = {};

    for (int k0 = 0; k0 < K; k0 += BKK) {
        #pragma unroll
        for (int i = 0; i < 4; ++i) {
            int c = i * 256 + tid;
            int r = c >> 3;
            int g = (c & 7) ^ (r & 7);
            const char* gpA = (const char*)A + ((size_t)(bm + r) * K + k0) * 2 + (g << 4);
            __builtin_amdgcn_global_load_lds(
                (const __attribute__((address_space(1))) void*)gpA,
                (__attribute__((address_space(3))) void*)(As + c * 16), 16, 0, 0);
        }
        #pragma unroll
        for (int i = 0; i < 2; ++i) {
            int c = i * 256 + tid;
            int r = c >> 3;
            int g = (c & 7) ^ (r & 7);
            const char* gpB = (const char*)Bt + ((size_t)(bn + r) * K + k0) * 2 + (g << 4);
            __builtin_amdgcn_global_load_lds(
                (const __attribute__((address_space(1))) void*)gpB,
                (__attribute__((address_space(3))) void*)(Bs + c * 16), 16, 0, 0);
        }
        __syncthreads();

        #pragma unroll
        for (int s = 0; s < 2; ++s) {
            bf16x8 af[4], bfr[2];
            int g = s * 4 + quad;
            #pragma unroll
            for (int i = 0; i < 4; ++i) {
                int r = wm * 64 + i * 16 + lq;
                af[i] = *(const bf16x8*)(As + r * 128 + ((g ^ (r & 7)) << 4));
            }
            #pragma unroll
            for (int j = 0; j < 2; ++j) {
                int n = wn * 32 + j * 16 + lq;
                bfr[j] = *(const bf16x8*)(Bs + n * 128 + ((g ^ (n & 7)) << 4));
            }
            #pragma unroll
            for (int i = 0; i < 4; ++i)
                #pragma unroll
                for (int j = 0; j < 2; ++j)
                    acc[i][j] = __builtin_amdgcn_mfma_f32_16x16x32_bf16(
                        af[i], bfr[j], acc[i][j], 0, 0, 0);
        }
        __syncthreads();
    }

    #pragma unroll
    for (int i = 0; i < 4; ++i) {
        #pragma unroll
        for (int p = 0; p < 4; ++p) {
            int r = bm + wm * 64 + i * 16 + quad * 4 + p;
            if (r < M) {
                #pragma unroll
                for (int j = 0; j < 2; ++j) {
                    int col = bn + wn * 32 + j * 16 + lq;
                    C[(size_t)r * HDIM + col] = f2bf(acc[i][j][p]);
                }
            }
        }
    }
}

// ---------------- dispatch 3: GEMM1 (640 blocks) + dinv compute (40) ----------
// dinv needs cnt complete (d2); GEMM needs xb+W1t (d1/d2). Independent, merged.
__global__ __launch_bounds__(256) void k_gemm1_dinv(
    const unsigned short* __restrict__ A, const unsigned short* __restrict__ Bt,
    unsigned short* __restrict__ C, int M, int K,
    const int* __restrict__ cnt, float* __restrict__ dinv) {
    int bx = blockIdx.x;
    if (bx < GG1) { gemm_body(A, Bt, C, M, K, bx); return; }
    int i = (bx - GG1) * 256 + threadIdx.x;
    if (i < NNODES) dinv[i] = rsqrtf((float)cnt[i] + 1.0f);
}

// ---------------- GEMM (layers 2/3) ----------------
__global__ __launch_bounds__(256) void k_gemm_bf16(
    const unsigned short* __restrict__ A, const unsigned short* __restrict__ Bt,
    unsigned short* __restrict__ C, int M, int K) {
    gemm_body(A, Bt, C, M, K, blockIdx.x);
}

// ---------------- aggregation (layers 1/2): 1 wave per node, bucket edges -----

__global__ void k_agg(const unsigned short* __restrict__ Y, const float* __restrict__ dinv,
                      const int* __restrict__ cnt, const int* __restrict__ bucket,
                      const float* __restrict__ bias, unsigned short* __restrict__ Hb) {
    int w = (blockIdx.x * blockDim.x + threadIdx.x) >> 6;
    int lane = threadIdx.x & 63;
    if (w >= MPAD) return;
    unsigned short* hr = Hb + (size_t)w * HDIM + lane * 8;
    if (w >= NNODES) {
        u16x8 z = {0, 0, 0, 0, 0, 0, 0, 0};
        *(u16x8*)hr = z;
        return;
    }
    float di = dinv[w];
    float sw = di * di;
    u16x8 own = *(const u16x8*)(Y + (size_t)w * HDIM + lane * 8);
    float acc[8];
    #pragma unroll
    for (int t = 0; t < 8; ++t) acc[t] = sw * bf2f(own[t]);

    const int* col = bucket + w * BCAP;
    int deg = cnt[w];
    int e = 0;
    for (; e + 4 <= deg; e += 4) {
        int s0 = col[e + 0], s1 = col[e + 1];
        int s2 = col[e + 2], s3 = col[e + 3];
        float w0 = di * dinv[s0], w1 = di * dinv[s1];
        float w2 = di * dinv[s2], w3 = di * dinv[s3];
        u16x8 v0 = *(const u16x8*)(Y + (size_t)s0 * HDIM + lane * 8);
        u16x8 v1 = *(const u16x8*)(Y + (size_t)s1 * HDIM + lane * 8);
        u16x8 v2 = *(const u16x8*)(Y + (size_t)s2 * HDIM + lane * 8);
        u16x8 v3 = *(const u16x8*)(Y + (size_t)s3 * HDIM + lane * 8);
        #pragma unroll
        for (int t = 0; t < 8; ++t) {
            acc[t] += w0 * bf2f(v0[t]);
            acc[t] += w1 * bf2f(v1[t]);
            acc[t] += w2 * bf2f(v2[t]);
            acc[t] += w3 * bf2f(v3[t]);
        }
    }
    for (; e < deg; ++e) {
        int s = col[e];
        float wg = di * dinv[s];
        u16x8 v = *(const u16x8*)(Y + (size_t)s * HDIM + lane * 8);
        #pragma unroll
        for (int t = 0; t < 8; ++t) acc[t] += wg * bf2f(v[t]);
    }

    float4 b0 = ((const float4*)bias)[lane * 2];
    float4 b1 = ((const float4*)bias)[lane * 2 + 1];
    acc[0] += b0.x; acc[1] += b0.y; acc[2] += b0.z; acc[3] += b0.w;
    acc[4] += b1.x; acc[5] += b1.y; acc[6] += b1.z; acc[7] += b1.w;
    u16x8 o;
    #pragma unroll
    for (int t = 0; t < 8; ++t) o[t] = f2bf(fmaxf(acc[t], 0.0f));
    *(u16x8*)hr = o;
}

// ---------------- agg3 + relu + layer-4 GEMM fused ----------------

__global__ void k_agg_g4(const unsigned short* __restrict__ Y, const float* __restrict__ dinv,
                         const int* __restrict__ cnt, const int* __restrict__ bucket,
                         const float* __restrict__ b3, const float* __restrict__ W4,
                         float* __restrict__ Y4) {
    int w = (blockIdx.x * blockDim.x + threadIdx.x) >> 6;
    int lane = threadIdx.x & 63;
    if (w >= NNODES) return;
    float di = dinv[w];
    float sw = di * di;
    u16x8 own = *(const u16x8*)(Y + (size_t)w * HDIM + lane * 8);
    float acc[8];
    #pragma unroll
    for (int t = 0; t < 8; ++t) acc[t] = sw * bf2f(own[t]);

    const int* col = bucket + w * BCAP;
    int deg = cnt[w];
    int e = 0;
    for (; e + 4 <= deg; e += 4) {
        int s0 = col[e + 0], s1 = col[e + 1];
        int s2 = col[e + 2], s3 = col[e + 3];
        float w0 = di * dinv[s0], w1 = di * dinv[s1];
        float w2 = di * dinv[s2], w3 = di * dinv[s3];
        u16x8 v0 = *(const u16x8*)(Y + (size_t)s0 * HDIM + lane * 8);
        u16x8 v1 = *(const u16x8*)(Y + (size_t)s1 * HDIM + lane * 8);
        u16x8 v2 = *(const u16x8*)(Y + (size_t)s2 * HDIM + lane * 8);
        u16x8 v3 = *(const u16x8*)(Y + (size_t)s3 * HDIM + lane * 8);
        #pragma unroll
        for (int t = 0; t < 8; ++t) {
            acc[t] += w0 * bf2f(v0[t]);
            acc[t] += w1 * bf2f(v1[t]);
            acc[t] += w2 * bf2f(v2[t]);
            acc[t] += w3 * bf2f(v3[t]);
        }
    }
    for (; e < deg; ++e) {
        int s = col[e];
        float wg = di * dinv[s];
        u16x8 v = *(const u16x8*)(Y + (size_t)s * HDIM + lane * 8);
        #pragma unroll
        for (int t = 0; t < 8; ++t) acc[t] += wg * bf2f(v[t]);
    }

    float4 b0 = ((const float4*)b3)[lane * 2];
    float4 b1 = ((const float4*)b3)[lane * 2 + 1];
    acc[0] += b0.x; acc[1] += b0.y; acc[2] += b0.z; acc[3] += b0.w;
    acc[4] += b1.x; acc[5] += b1.y; acc[6] += b1.z; acc[7] += b1.w;
    #pragma unroll
    for (int t = 0; t < 8; ++t) acc[t] = fmaxf(acc[t], 0.0f);

    const float4* wf = (const float4*)W4;
    float4 w0 = wf[lane * 4 + 0];
    float4 w1 = wf[lane * 4 + 1];
    float4 w2 = wf[lane * 4 + 2];
    float4 w3 = wf[lane * 4 + 3];
    float z0 = acc[0]*w0.x + acc[1]*w0.z + acc[2]*w1.x + acc[3]*w1.z
             + acc[4]*w2.x + acc[5]*w2.z + acc[6]*w3.x + acc[7]*w3.z;
    float z1 = acc[0]*w0.y + acc[1]*w0.w + acc[2]*w1.y + acc[3]*w1.w
             + acc[4]*w2.y + acc[5]*w2.w + acc[6]*w3.y + acc[7]*w3.w;
    #pragma unroll
    for (int off = 32; off > 0; off >>= 1) {
        z0 += __shfl_down(z0, off);
        z1 += __shfl_down(z1, off);
    }
    if (lane == 0) {
        Y4[2 * w] = z0;
        Y4[2 * w + 1] = z1;
    }
}

// ---------------- layer-4 aggregation + bias + log_softmax ----------------

__global__ void k_final(const float* __restrict__ Y4, const float* __restrict__ dinv,
                        const int* __restrict__ cnt, const int* __restrict__ bucket,
                        const float* __restrict__ b4, float* __restrict__ out, int n) {
    int i = blockIdx.x * blockDim.x + threadIdx.x;
    if (i >= n) return;
    float di = dinv[i];
    float sw = di * di;
    float z0 = sw * Y4[2 * i];
    float z1 = sw * Y4[2 * i + 1];
    const int* col = bucket + i * BCAP;
    int deg = cnt[i];
    for (int e = 0; e < deg; ++e) {
        int s = col[e];
        float wgt = di * dinv[s];
        z0 += wgt * Y4[2 * s];
        z1 += wgt * Y4[2 * s + 1];
    }
    z0 += b4[0];
    z1 += b4[1];
    float m = fmaxf(z0, z1);
    float l = m + logf(expf(z0 - m) + expf(z1 - m));
    out[2 * i] = z0 - l;
    out[2 * i + 1] = z1 - l;
}

// ---------------- launch ----------------

extern "C" void kernel_launch(void* const* d_in, const int* in_sizes, int n_in,
                              void* d_out, int out_size, void* d_ws, size_t ws_size,
                              hipStream_t stream) {
    const float* x  = (const float*)d_in[0];
    const int*   ei = (const int*)d_in[1];
    const float* W1 = (const float*)d_in[3];
    const float* b1 = (const float*)d_in[4];
    const float* W2 = (const float*)d_in[5];
    const float* b2 = (const float*)d_in[6];
    const float* W3 = (const float*)d_in[7];
    const float* b3 = (const float*)d_in[8];
    const float* W4 = (const float*)d_in[9];
    const float* b4 = (const float*)d_in[10];
    float* out = (float*)d_out;

    char* ws = (char*)d_ws;
    // workspace layout (bytes, 256-aligned)
    float*          dinv    = (float*)(ws + 0);                  // 40,960
    int*            cnt     = (int*)  (ws + 40960);              // 40,960
    int*            bucket  = (int*)  (ws + 81920);              // NNODES*BCAP*4 = 5,120,000
    float*          Y4      = (float*)(ws + 5201920);            // 81,920
    unsigned short* xb      = (unsigned short*)(ws + 5283840);   // 45,875,200
    unsigned short* W1t     = (unsigned short*)(ws + 51159040);  // 2,293,760
    unsigned short* W2t     = (unsigned short*)(ws + 53452800);  // 524,288
    unsigned short* W3t     = (unsigned short*)(ws + 53977088);  // 524,288
    unsigned short* Yb      = (unsigned short*)(ws + 54501376);  // 10,485,760
    unsigned short* Hb      = (unsigned short*)(ws + 64987136);  // 10,485,760
    // total: 75,472,896
    if (ws_size < 75472896) return;

    const int agrid = (MPAD * 64) / 256;  // one wave per (padded) node

    // d1: weight transposes + cnt zero
    k_prep<<<dim3(14, HDIM), 256, 0, stream>>>(W1, W2, W3, W1t, W2t, W3t, cnt);
    // d2: x->bf16 convert + bucketed hist/fill (no scan needed)
    k_cvt_fill<<<MPAD + 625, 256, 0, stream>>>(x, xb, ei, cnt, bucket);
    // d3: layer-1 GEMM + dinv compute (merged)
    k_gemm1_dinv<<<GG1 + 40, 256, 0, stream>>>(xb, W1t, Yb, NNODES, K1PAD, cnt, dinv);
    // d4: layer-1 aggregation
    k_agg<<<agrid, 256, 0, stream>>>(Yb, dinv, cnt, bucket, b1, Hb);
    // d5/d6: layer 2
    k_gemm_bf16<<<GG1, 256, 0, stream>>>(Hb, W2t, Yb, NNODES, HDIM);
    k_agg<<<agrid, 256, 0, stream>>>(Yb, dinv, cnt, bucket, b2, Hb);
    // d7/d8: layer 3 + fused layer-4 GEMM
    k_gemm_bf16<<<GG1, 256, 0, stream>>>(Hb, W3t, Yb, NNODES, HDIM);
    k_agg_g4<<<(NNODES * 64) / 256, 256, 0, stream>>>(Yb, dinv, cnt, bucket, b3, W4, Y4);
    // d9: layer-4 aggregation + log_softmax
    k_final<<<40, 256, 0, stream>>>(Y4, dinv, cnt, bucket, b4, out, NNODES);
}